// Round 5
// baseline (4274.591 us; speedup 1.0000x reference)
//
#include <hip/hip_runtime.h>
#include <math.h>

#define BATCH 256
#define TT    784
#define HH    512
#define NCLS  10

#define NB 32          // batch groups
#define NJ 8           // j groups (blocks per group) == waves per block
#define MB 8           // batch rows per group   (BATCH/NB)
#define HJ 64          // output cols per block  (HH/NJ)
#define NT 512         // threads per block (8 waves)

typedef unsigned long long ull;
typedef unsigned int uint32;

#define AL(p)    __hip_atomic_load((p), __ATOMIC_RELAXED, __HIP_MEMORY_SCOPE_AGENT)
#define AS(p, v) __hip_atomic_store((p), (v), __ATOMIC_RELAXED, __HIP_MEMORY_SCOPE_AGENT)

// d_ws layout: double-buffered TAGGED h state, 2 * B * H ull (2 MB).
// Each element is (hi32 = step tag, lo32 = f32 bits). Producer at end of
// step t writes tag t+1 into buf[(t+1)&1]; consumer at step t spins on
// buf[t&1] until tag == t. Data and readiness travel in ONE sc1 packet ->
// one L3 trip on the critical path, no flags, no vmcnt-drain+release.

__global__ __launch_bounds__(256) void rnn_init_kernel(ull* hbT) {
    const int i = blockIdx.x * blockDim.x + threadIdx.x;     // 65536 threads
    AS(&hbT[i],           0ULL);                             // buf0: h=0, tag=0
    AS(&hbT[i +  65536],  0ULL);
    AS(&hbT[i + 131072],  0xFFFFFFFF00000000ULL);            // buf1: never-match tag
    AS(&hbT[i + 196608],  0xFFFFFFFF00000000ULL);
}

__global__ __launch_bounds__(NT, 2) void rnn_main_kernel(
    const float* __restrict__ inputs, const int* __restrict__ order,
    const float* __restrict__ W_ih, const float* __restrict__ b_ih,
    const float* __restrict__ W_hh, const float* __restrict__ b_hh,
    ull* __restrict__ hbT)
{
    __shared__ float hp[MB * HH];            // 16 KB: h tile (global col layout)
    __shared__ float pbuf[32 * MB * HJ];     // 64 KB: partials [kg][b][j*4+cg]
    __shared__ float xall[TT * MB];          // 25 KB: pre-gathered inputs[b][order[t]]
    __shared__ float wih_s[HJ];
    __shared__ float bias_s[HJ];

    const int tid   = threadIdx.x;
    const int blk   = blockIdx.x;
    const int bb    = blk & (NB - 1);
    const int jjg   = blk >> 5;         // j group 0..7 (this block produces cols [jjg*64, +64))
    const int jbase = jjg * HJ;
    const int bbase = bb * MB;
    const int j   = tid & 15;           // compute map: base column lane
    const int kg  = tid >> 4;           // k-chunk 0..31 (16 k each); wave w = kg>>2
    const int kg4 = kg * 4;
    const int w   = tid >> 6;           // wave index == the ONE producer this wave depends on
    const int l   = tid & 63;
    const int r   = l >> 3;             // staging map: batch row 0..7
    const int c8  = l & 7;              // staging map: 8-ull chunk within the 64-col slice
    const int colbase = w * 64 + c8 * 8;

    // ---- W_hh slice in NAMED registers: 4 cols x 16 k = 16 float4
    const float4* wp0 = (const float4*)(W_hh + (size_t)(jbase + j +  0) * HH + kg * 16);
    const float4* wp1 = (const float4*)(W_hh + (size_t)(jbase + j + 16) * HH + kg * 16);
    const float4* wp2 = (const float4*)(W_hh + (size_t)(jbase + j + 32) * HH + kg * 16);
    const float4* wp3 = (const float4*)(W_hh + (size_t)(jbase + j + 48) * HH + kg * 16);
    const float4 wa0 = wp0[0], wa1 = wp0[1], wa2 = wp0[2], wa3 = wp0[3];
    const float4 wb0 = wp1[0], wb1 = wp1[1], wb2 = wp1[2], wb3 = wp1[3];
    const float4 wc0 = wp2[0], wc1 = wp2[1], wc2 = wp2[2], wc3 = wp2[3];
    const float4 wd0 = wp3[0], wd1 = wp3[1], wd2 = wp3[2], wd3 = wp3[3];

    if (tid < HJ) {
        wih_s[tid]  = W_ih[jbase + tid];
        bias_s[tid] = b_ih[jbase + tid] + b_hh[jbase + tid];
    }
    for (int idx = tid; idx < TT * MB; idx += NT) {
        const int t = idx >> 3;
        const int b = idx & (MB - 1);
        xall[idx] = inputs[(size_t)(bbase + b) * TT + order[t]];
    }
    __syncthreads();                     // xall/wih/bias ready

    const float4* hp4 = (const float4*)hp;
    float2* hp2 = (float2*)hp;
    float4* P4 = (float4*)pbuf;

    for (int t = 0; t < TT; ++t) {
        const int p = t & 1;

        // ---- per-wave staging: tag-poll ONLY producer w's slice, into own hp region.
        //      (wave jjg's slice was written locally by the reducers last step, except t=0)
        if (t == 0 || w != jjg) {
            const ull* src = hbT + (size_t)p * BATCH * HH + (size_t)(bbase + r) * HH + colbase;
            ull u0 = AL(src + 0), u1 = AL(src + 1), u2 = AL(src + 2), u3 = AL(src + 3);
            ull u4 = AL(src + 4), u5 = AL(src + 5), u6 = AL(src + 6), u7 = AL(src + 7);
            const uint32 tg = (uint32)t;
            while ((uint32)(u0 >> 32) != tg) u0 = AL(src + 0);
            while ((uint32)(u1 >> 32) != tg) u1 = AL(src + 1);
            while ((uint32)(u2 >> 32) != tg) u2 = AL(src + 2);
            while ((uint32)(u3 >> 32) != tg) u3 = AL(src + 3);
            while ((uint32)(u4 >> 32) != tg) u4 = AL(src + 4);
            while ((uint32)(u5 >> 32) != tg) u5 = AL(src + 5);
            while ((uint32)(u6 >> 32) != tg) u6 = AL(src + 6);
            while ((uint32)(u7 >> 32) != tg) u7 = AL(src + 7);
            const int di = (r * HH + colbase) >> 1;     // float2 index
            hp2[di + 0] = make_float2(__uint_as_float((uint32)u0), __uint_as_float((uint32)u1));
            hp2[di + 1] = make_float2(__uint_as_float((uint32)u2), __uint_as_float((uint32)u3));
            hp2[di + 2] = make_float2(__uint_as_float((uint32)u4), __uint_as_float((uint32)u5));
            hp2[di + 3] = make_float2(__uint_as_float((uint32)u6), __uint_as_float((uint32)u7));
        }
        // intra-wave LDS visibility: compiler inserts lgkmcnt before the hp reads below;
        // wave-synchronous execution makes cross-lane-same-wave writes visible. No barrier.

        // ---- partial dot products: this wave reads ONLY hp cols [64w, 64w+64)
        float a00=0.f,a01=0.f,a02=0.f,a03=0.f,a04=0.f,a05=0.f,a06=0.f,a07=0.f;
        float a10=0.f,a11=0.f,a12=0.f,a13=0.f,a14=0.f,a15=0.f,a16=0.f,a17=0.f;
        float a20=0.f,a21=0.f,a22=0.f,a23=0.f,a24=0.f,a25=0.f,a26=0.f,a27=0.f;
        float a30=0.f,a31=0.f,a32=0.f,a33=0.f,a34=0.f,a35=0.f,a36=0.f,a37=0.f;

#define FMA4(ACC, WV, HV) \
        ACC = fmaf(WV.x, HV.x, ACC); ACC = fmaf(WV.y, HV.y, ACC); \
        ACC = fmaf(WV.z, HV.z, ACC); ACC = fmaf(WV.w, HV.w, ACC);
#define ROW(B) { \
        const float4* hr = hp4 + (B)*128 + kg4; \
        const float4 h0 = hr[0], h1 = hr[1], h2 = hr[2], h3 = hr[3]; \
        FMA4(a0##B, wa0, h0) FMA4(a0##B, wa1, h1) FMA4(a0##B, wa2, h2) FMA4(a0##B, wa3, h3) \
        FMA4(a1##B, wb0, h0) FMA4(a1##B, wb1, h1) FMA4(a1##B, wb2, h2) FMA4(a1##B, wb3, h3) \
        FMA4(a2##B, wc0, h0) FMA4(a2##B, wc1, h1) FMA4(a2##B, wc2, h2) FMA4(a2##B, wc3, h3) \
        FMA4(a3##B, wd0, h0) FMA4(a3##B, wd1, h1) FMA4(a3##B, wd2, h2) FMA4(a3##B, wd3, h3) }

        ROW(0) ROW(1) ROW(2) ROW(3) ROW(4) ROW(5) ROW(6) ROW(7)
#undef ROW
#undef FMA4

        {
            float4* dst = P4 + (size_t)kg * 128 + j;
            dst[0*16] = make_float4(a00, a10, a20, a30);
            dst[1*16] = make_float4(a01, a11, a21, a31);
            dst[2*16] = make_float4(a02, a12, a22, a32);
            dst[3*16] = make_float4(a03, a13, a23, a33);
            dst[4*16] = make_float4(a04, a14, a24, a34);
            dst[5*16] = make_float4(a05, a15, a25, a35);
            dst[6*16] = make_float4(a06, a16, a26, a36);
            dst[7*16] = make_float4(a07, a17, a27, a37);
        }
        __syncthreads();                 // B: all partials ready

        // ---- reduce 32 k-chunks (2 waves), tanh, publish tagged h (sc1) + own-slice to LDS
        if (tid < 128) {
            const int rb = tid >> 4;
            const int rj = tid & 15;
            float4 s = P4[rb * 16 + rj];
            #pragma unroll
            for (int g = 1; g < 32; ++g) {
                const float4 v = P4[(size_t)g * 128 + rb * 16 + rj];
                s.x += v.x; s.y += v.y; s.z += v.z; s.w += v.w;
            }
            const float xv = xall[t * MB + rb];
            const float h0 = tanhf(s.x + xv * wih_s[rj +  0] + bias_s[rj +  0]);
            const float h1 = tanhf(s.y + xv * wih_s[rj + 16] + bias_s[rj + 16]);
            const float h2 = tanhf(s.z + xv * wih_s[rj + 32] + bias_s[rj + 32]);
            const float h3 = tanhf(s.w + xv * wih_s[rj + 48] + bias_s[rj + 48]);
            ull* drow = hbT + (size_t)(p ^ 1) * BATCH * HH + (size_t)(bbase + rb) * HH + jbase;
            const ull tg = ((ull)(uint32)(t + 1)) << 32;
            AS(&drow[rj +  0], tg | (ull)__float_as_uint(h0));
            AS(&drow[rj + 16], tg | (ull)__float_as_uint(h1));
            AS(&drow[rj + 32], tg | (ull)__float_as_uint(h2));
            AS(&drow[rj + 48], tg | (ull)__float_as_uint(h3));
            // own slice shortcut: next step, wave jjg reads these from LDS directly
            hp[rb * HH + jbase + rj +  0] = h0;
            hp[rb * HH + jbase + rj + 16] = h1;
            hp[rb * HH + jbase + rj + 32] = h2;
            hp[rb * HH + jbase + rj + 48] = h3;
        }
        __syncthreads();                 // C: pbuf WAR + own-slice visible to wave jjg
    }
}

__global__ __launch_bounds__(256) void rnn_tail_kernel(
    const ull* __restrict__ hfinT,    // final tagged h in buf 0 (T even)
    const float* __restrict__ lin_W, const float* __restrict__ lin_b,
    const int* __restrict__ y, float* __restrict__ out)
{
    __shared__ float redf[256];
    __shared__ int   redi[256];
    const int b = threadIdx.x;
    const ull* hrow = hfinT + (size_t)b * HH;

    float hv[8];
    float logits[NCLS];
    #pragma unroll
    for (int c = 0; c < NCLS; ++c) logits[c] = lin_b[c];
    for (int k = 0; k < HH; k += 8) {
        #pragma unroll
        for (int i = 0; i < 8; ++i) hv[i] = __uint_as_float((uint32)hrow[k + i]);
        #pragma unroll
        for (int c = 0; c < NCLS; ++c) {
            const float* wrow = lin_W + (size_t)c * HH + k;
            float s = logits[c];
            #pragma unroll
            for (int i = 0; i < 8; ++i) s += hv[i] * wrow[i];
            logits[c] = s;
        }
    }
    int am = 0; float m = logits[0];
    #pragma unroll
    for (int c = 1; c < NCLS; ++c) if (logits[c] > m) { m = logits[c]; am = c; } // first-max = jnp.argmax
    float sum = 0.0f;
    #pragma unroll
    for (int c = 0; c < NCLS; ++c) sum += expf(logits[c] - m);
    const float lse = m + logf(sum);
    const int yy = y[b];
    redf[b] = lse - logits[yy];
    redi[b] = (am == yy) ? 1 : 0;
    __syncthreads();
    for (int s2 = 128; s2 > 0; s2 >>= 1) {
        if (b < s2) { redf[b] += redf[b + s2]; redi[b] += redi[b + s2]; }
        __syncthreads();
    }
    if (b == 0) {
        out[0] = redf[0] / (float)BATCH;
        out[1] = (float)redi[0];
    }
}

extern "C" void kernel_launch(void* const* d_in, const int* in_sizes, int n_in,
                              void* d_out, int out_size, void* d_ws, size_t ws_size,
                              hipStream_t stream) {
    const float* inputs = (const float*)d_in[0];
    const int*   y      = (const int*)  d_in[1];
    const int*   order  = (const int*)  d_in[2];
    const float* W_ih   = (const float*)d_in[3];
    const float* b_ih   = (const float*)d_in[4];
    const float* W_hh   = (const float*)d_in[5];
    const float* b_hh   = (const float*)d_in[6];
    const float* lin_W  = (const float*)d_in[7];
    const float* lin_b  = (const float*)d_in[8];
    float* out = (float*)d_out;

    ull* hbT = (ull*)d_ws;               // 2 MB tagged double buffer

    hipLaunchKernelGGL(rnn_init_kernel, dim3(256), dim3(256), 0, stream, hbT);

    void* args[] = {(void*)&inputs, (void*)&order, (void*)&W_ih, (void*)&b_ih,
                    (void*)&W_hh, (void*)&b_hh, (void*)&hbT};
    hipError_t err = hipLaunchCooperativeKernel((void*)rnn_main_kernel,
                                                dim3(NB * NJ), dim3(NT), args, 0, stream);
    if (err != hipSuccess) {
        hipLaunchKernelGGL(rnn_main_kernel, dim3(NB * NJ), dim3(NT), 0, stream,
                           inputs, order, W_ih, b_ih, W_hh, b_hh, hbT);
    }

    hipLaunchKernelGGL(rnn_tail_kernel, dim3(1), dim3(256), 0, stream,
                       hbT, lin_W, lin_b, y, out);
}

// Round 6
// 4270.607 us; speedup vs baseline: 1.0009x; 1.0009x over previous
//
#include <hip/hip_runtime.h>
#include <math.h>

#define BATCH 256
#define TT    784
#define HH    512
#define NCLS  10

#define NB 32          // batch groups
#define NJ 8           // j groups (blocks per group) == waves per block
#define MB 8           // batch rows per group   (BATCH/NB)
#define HJ 64          // output cols per block  (HH/NJ)
#define NT 512         // threads per block (8 waves)

typedef unsigned long long ull;
typedef unsigned int uint32;

#define AL(p)    __hip_atomic_load((p), __ATOMIC_RELAXED, __HIP_MEMORY_SCOPE_AGENT)
#define AS(p, v) __hip_atomic_store((p), (v), __ATOMIC_RELAXED, __HIP_MEMORY_SCOPE_AGENT)

// d_ws layout: double-buffered TAGGED h state, 2 * B * H ull (2 MB).
// Each element is (hi32 = step tag, lo32 = f32 bits). Producer at end of
// step t writes tag t+1 into buf[(t+1)&1]; consumer at step t spins on
// buf[t&1] until tag == t. Data and readiness travel in ONE sc1 packet ->
// one L3 trip on the critical path. Poll loop issues ALL 8 loads per round
// (parallel, 1 RTT/round) -- R5's serial per-packet loops were the bug.

__global__ __launch_bounds__(256) void rnn_init_kernel(ull* hbT) {
    const int i = blockIdx.x * blockDim.x + threadIdx.x;     // 65536 threads
    AS(&hbT[i],           0ULL);                             // buf0: h=0, tag=0
    AS(&hbT[i +  65536],  0ULL);
    AS(&hbT[i + 131072],  0xFFFFFFFF00000000ULL);            // buf1: never-match tag
    AS(&hbT[i + 196608],  0xFFFFFFFF00000000ULL);
}

__global__ __launch_bounds__(NT, 2) void rnn_main_kernel(
    const float* __restrict__ inputs, const int* __restrict__ order,
    const float* __restrict__ W_ih, const float* __restrict__ b_ih,
    const float* __restrict__ W_hh, const float* __restrict__ b_hh,
    ull* __restrict__ hbT)
{
    __shared__ float hp[MB * HH];            // 16 KB: h tile (global col layout)
    __shared__ float pbuf[32 * MB * HJ];     // 64 KB: partials [kg][b][j*4+cg]
    __shared__ float xall[TT * MB];          // 25 KB: pre-gathered inputs[b][order[t]]
    __shared__ float wih_s[HJ];
    __shared__ float bias_s[HJ];

    const int tid   = threadIdx.x;
    const int blk   = blockIdx.x;
    const int bb    = blk & (NB - 1);
    const int jjg   = blk >> 5;         // j group 0..7 (this block produces cols [jjg*64, +64))
    const int jbase = jjg * HJ;
    const int bbase = bb * MB;
    const int j   = tid & 15;           // compute map: base column lane
    const int kg  = tid >> 4;           // k-chunk 0..31 (16 k each); wave w = kg>>2
    const int kg4 = kg * 4;
    const int w   = tid >> 6;           // wave index == the ONE producer this wave depends on
    const int l   = tid & 63;
    const int r   = l >> 3;             // staging map: batch row 0..7
    const int c8  = l & 7;              // staging map: 8-ull chunk within the 64-col slice
    const int colbase = w * 64 + c8 * 8;

    // ---- W_hh slice in NAMED registers: 4 cols x 16 k = 16 float4
    const float4* wp0 = (const float4*)(W_hh + (size_t)(jbase + j +  0) * HH + kg * 16);
    const float4* wp1 = (const float4*)(W_hh + (size_t)(jbase + j + 16) * HH + kg * 16);
    const float4* wp2 = (const float4*)(W_hh + (size_t)(jbase + j + 32) * HH + kg * 16);
    const float4* wp3 = (const float4*)(W_hh + (size_t)(jbase + j + 48) * HH + kg * 16);
    const float4 wa0 = wp0[0], wa1 = wp0[1], wa2 = wp0[2], wa3 = wp0[3];
    const float4 wb0 = wp1[0], wb1 = wp1[1], wb2 = wp1[2], wb3 = wp1[3];
    const float4 wc0 = wp2[0], wc1 = wp2[1], wc2 = wp2[2], wc3 = wp2[3];
    const float4 wd0 = wp3[0], wd1 = wp3[1], wd2 = wp3[2], wd3 = wp3[3];

    if (tid < HJ) {
        wih_s[tid]  = W_ih[jbase + tid];
        bias_s[tid] = b_ih[jbase + tid] + b_hh[jbase + tid];
    }
    for (int idx = tid; idx < TT * MB; idx += NT) {
        const int t = idx >> 3;
        const int b = idx & (MB - 1);
        xall[idx] = inputs[(size_t)(bbase + b) * TT + order[t]];
    }
    __syncthreads();                     // xall/wih/bias ready

    const float4* hp4 = (const float4*)hp;
    float2* hp2 = (float2*)hp;
    float4* P4 = (float4*)pbuf;

    for (int t = 0; t < TT; ++t) {
        const int p = t & 1;

        // ---- per-wave staging: tag-poll ONLY producer w's slice, into own hp region.
        //      (wave jjg's slice was written locally by the reducers last step, except t=0)
        if (t == 0 || w != jjg) {
            const ull* src = hbT + (size_t)p * BATCH * HH + (size_t)(bbase + r) * HH + colbase;
            const uint32 tg = (uint32)t;
            ull u0, u1, u2, u3, u4, u5, u6, u7;
            for (;;) {
                // all 8 loads issued back-to-back: one L3 round trip per poll round
                u0 = AL(src + 0); u1 = AL(src + 1); u2 = AL(src + 2); u3 = AL(src + 3);
                u4 = AL(src + 4); u5 = AL(src + 5); u6 = AL(src + 6); u7 = AL(src + 7);
                const uint32 bad = ((uint32)(u0 >> 32) ^ tg) | ((uint32)(u1 >> 32) ^ tg)
                                 | ((uint32)(u2 >> 32) ^ tg) | ((uint32)(u3 >> 32) ^ tg)
                                 | ((uint32)(u4 >> 32) ^ tg) | ((uint32)(u5 >> 32) ^ tg)
                                 | ((uint32)(u6 >> 32) ^ tg) | ((uint32)(u7 >> 32) ^ tg);
                if (bad == 0) break;
                __builtin_amdgcn_s_sleep(1);   // ~64 cyc backoff: cut L3 poll storm
            }
            const int di = (r * HH + colbase) >> 1;     // float2 index
            hp2[di + 0] = make_float2(__uint_as_float((uint32)u0), __uint_as_float((uint32)u1));
            hp2[di + 1] = make_float2(__uint_as_float((uint32)u2), __uint_as_float((uint32)u3));
            hp2[di + 2] = make_float2(__uint_as_float((uint32)u4), __uint_as_float((uint32)u5));
            hp2[di + 3] = make_float2(__uint_as_float((uint32)u6), __uint_as_float((uint32)u7));
        }
        // intra-wave LDS RAW: compiler inserts lgkmcnt before the hp reads below. No barrier.

        // ---- partial dot products: this wave reads ONLY hp cols [64w, 64w+64)
        float a00=0.f,a01=0.f,a02=0.f,a03=0.f,a04=0.f,a05=0.f,a06=0.f,a07=0.f;
        float a10=0.f,a11=0.f,a12=0.f,a13=0.f,a14=0.f,a15=0.f,a16=0.f,a17=0.f;
        float a20=0.f,a21=0.f,a22=0.f,a23=0.f,a24=0.f,a25=0.f,a26=0.f,a27=0.f;
        float a30=0.f,a31=0.f,a32=0.f,a33=0.f,a34=0.f,a35=0.f,a36=0.f,a37=0.f;

#define FMA4(ACC, WV, HV) \
        ACC = fmaf(WV.x, HV.x, ACC); ACC = fmaf(WV.y, HV.y, ACC); \
        ACC = fmaf(WV.z, HV.z, ACC); ACC = fmaf(WV.w, HV.w, ACC);
#define ROW(B) { \
        const float4* hr = hp4 + (B)*128 + kg4; \
        const float4 h0 = hr[0], h1 = hr[1], h2 = hr[2], h3 = hr[3]; \
        FMA4(a0##B, wa0, h0) FMA4(a0##B, wa1, h1) FMA4(a0##B, wa2, h2) FMA4(a0##B, wa3, h3) \
        FMA4(a1##B, wb0, h0) FMA4(a1##B, wb1, h1) FMA4(a1##B, wb2, h2) FMA4(a1##B, wb3, h3) \
        FMA4(a2##B, wc0, h0) FMA4(a2##B, wc1, h1) FMA4(a2##B, wc2, h2) FMA4(a2##B, wc3, h3) \
        FMA4(a3##B, wd0, h0) FMA4(a3##B, wd1, h1) FMA4(a3##B, wd2, h2) FMA4(a3##B, wd3, h3) }

        ROW(0) ROW(1) ROW(2) ROW(3) ROW(4) ROW(5) ROW(6) ROW(7)
#undef ROW
#undef FMA4

        {
            float4* dst = P4 + (size_t)kg * 128 + j;
            dst[0*16] = make_float4(a00, a10, a20, a30);
            dst[1*16] = make_float4(a01, a11, a21, a31);
            dst[2*16] = make_float4(a02, a12, a22, a32);
            dst[3*16] = make_float4(a03, a13, a23, a33);
            dst[4*16] = make_float4(a04, a14, a24, a34);
            dst[5*16] = make_float4(a05, a15, a25, a35);
            dst[6*16] = make_float4(a06, a16, a26, a36);
            dst[7*16] = make_float4(a07, a17, a27, a37);
        }
        __syncthreads();                 // B: all partials ready

        // ---- reduce 32 k-chunks (2 waves), tanh, publish tagged h (sc1) + own-slice to LDS
        if (tid < 128) {
            const int rb = tid >> 4;
            const int rj = tid & 15;
            float4 s = P4[rb * 16 + rj];
            #pragma unroll
            for (int g = 1; g < 32; ++g) {
                const float4 v = P4[(size_t)g * 128 + rb * 16 + rj];
                s.x += v.x; s.y += v.y; s.z += v.z; s.w += v.w;
            }
            const float xv = xall[t * MB + rb];
            const float h0 = tanhf(s.x + xv * wih_s[rj +  0] + bias_s[rj +  0]);
            const float h1 = tanhf(s.y + xv * wih_s[rj + 16] + bias_s[rj + 16]);
            const float h2 = tanhf(s.z + xv * wih_s[rj + 32] + bias_s[rj + 32]);
            const float h3 = tanhf(s.w + xv * wih_s[rj + 48] + bias_s[rj + 48]);
            ull* drow = hbT + (size_t)(p ^ 1) * BATCH * HH + (size_t)(bbase + rb) * HH + jbase;
            const ull tg = ((ull)(uint32)(t + 1)) << 32;
            AS(&drow[rj +  0], tg | (ull)__float_as_uint(h0));
            AS(&drow[rj + 16], tg | (ull)__float_as_uint(h1));
            AS(&drow[rj + 32], tg | (ull)__float_as_uint(h2));
            AS(&drow[rj + 48], tg | (ull)__float_as_uint(h3));
            // own slice shortcut: next step, wave jjg reads these from LDS directly
            hp[rb * HH + jbase + rj +  0] = h0;
            hp[rb * HH + jbase + rj + 16] = h1;
            hp[rb * HH + jbase + rj + 32] = h2;
            hp[rb * HH + jbase + rj + 48] = h3;
        }
        __syncthreads();                 // C: pbuf WAR + own-slice visible to wave jjg
    }
}

__global__ __launch_bounds__(256) void rnn_tail_kernel(
    const ull* __restrict__ hfinT,    // final tagged h in buf 0 (T even)
    const float* __restrict__ lin_W, const float* __restrict__ lin_b,
    const int* __restrict__ y, float* __restrict__ out)
{
    __shared__ float redf[256];
    __shared__ int   redi[256];
    const int b = threadIdx.x;
    const ull* hrow = hfinT + (size_t)b * HH;

    float hv[8];
    float logits[NCLS];
    #pragma unroll
    for (int c = 0; c < NCLS; ++c) logits[c] = lin_b[c];
    for (int k = 0; k < HH; k += 8) {
        #pragma unroll
        for (int i = 0; i < 8; ++i) hv[i] = __uint_as_float((uint32)hrow[k + i]);
        #pragma unroll
        for (int c = 0; c < NCLS; ++c) {
            const float* wrow = lin_W + (size_t)c * HH + k;
            float s = logits[c];
            #pragma unroll
            for (int i = 0; i < 8; ++i) s += hv[i] * wrow[i];
            logits[c] = s;
        }
    }
    int am = 0; float m = logits[0];
    #pragma unroll
    for (int c = 1; c < NCLS; ++c) if (logits[c] > m) { m = logits[c]; am = c; } // first-max = jnp.argmax
    float sum = 0.0f;
    #pragma unroll
    for (int c = 0; c < NCLS; ++c) sum += expf(logits[c] - m);
    const float lse = m + logf(sum);
    const int yy = y[b];
    redf[b] = lse - logits[yy];
    redi[b] = (am == yy) ? 1 : 0;
    __syncthreads();
    for (int s2 = 128; s2 > 0; s2 >>= 1) {
        if (b < s2) { redf[b] += redf[b + s2]; redi[b] += redi[b + s2]; }
        __syncthreads();
    }
    if (b == 0) {
        out[0] = redf[0] / (float)BATCH;
        out[1] = (float)redi[0];
    }
}

extern "C" void kernel_launch(void* const* d_in, const int* in_sizes, int n_in,
                              void* d_out, int out_size, void* d_ws, size_t ws_size,
                              hipStream_t stream) {
    const float* inputs = (const float*)d_in[0];
    const int*   y      = (const int*)  d_in[1];
    const int*   order  = (const int*)  d_in[2];
    const float* W_ih   = (const float*)d_in[3];
    const float* b_ih   = (const float*)d_in[4];
    const float* W_hh   = (const float*)d_in[5];
    const float* b_hh   = (const float*)d_in[6];
    const float* lin_W  = (const float*)d_in[7];
    const float* lin_b  = (const float*)d_in[8];
    float* out = (float*)d_out;

    ull* hbT = (ull*)d_ws;               // 2 MB tagged double buffer

    hipLaunchKernelGGL(rnn_init_kernel, dim3(256), dim3(256), 0, stream, hbT);

    void* args[] = {(void*)&inputs, (void*)&order, (void*)&W_ih, (void*)&b_ih,
                    (void*)&W_hh, (void*)&b_hh, (void*)&hbT};
    hipError_t err = hipLaunchCooperativeKernel((void*)rnn_main_kernel,
                                                dim3(NB * NJ), dim3(NT), args, 0, stream);
    if (err != hipSuccess) {
        hipLaunchKernelGGL(rnn_main_kernel, dim3(NB * NJ), dim3(NT), 0, stream,
                           inputs, order, W_ih, b_ih, W_hh, b_hh, hbT);
    }

    hipLaunchKernelGGL(rnn_tail_kernel, dim3(1), dim3(256), 0, stream,
                       hbT, lin_W, lin_b, y, out);
}